// Round 1
// baseline (743.884 us; speedup 1.0000x reference)
//
#include <hip/hip_runtime.h>
#include <hip/hip_bf16.h>

// EnhancedReprogrammingLayer: Q/K/V projections (bf16 MFMA), fused flash
// cross-attention over S=1000 prototypes, output projection to 4096.
// B=8, L=1024, H=8, E=128, D_MODEL=1024, D_LLM=4096, dk=1024.

typedef __attribute__((ext_vector_type(8))) short short8;
typedef __attribute__((ext_vector_type(4))) float f32x4;

#define DEVINL static __device__ __forceinline__

DEVINL unsigned short f2bf(float f) {
  union { float f; unsigned u; } v; v.f = f;
  unsigned r = v.u + 0x7FFFu + ((v.u >> 16) & 1u);
  return (unsigned short)(r >> 16);
}

DEVINL f32x4 zero4() { f32x4 z; z[0] = 0.f; z[1] = 0.f; z[2] = 0.f; z[3] = 0.f; return z; }
DEVINL short8 zero8() { short8 z; z[0]=0; z[1]=0; z[2]=0; z[3]=0; z[4]=0; z[5]=0; z[6]=0; z[7]=0; return z; }

// C[M][N] = A[M][K] @ B[N][K]^T + bias.  A fp32 or bf16(ushort); B,bias fp32.
// Block tile 128x128, BK=32, 4 waves in 2x2, each wave 64x64 (4x4 MFMA tiles).
template<bool A_BF16, bool C_BF16>
__global__ __launch_bounds__(256)
void gemm_bt(const void* __restrict__ A_, const float* __restrict__ B,
             const float* __restrict__ bias, void* __restrict__ C_,
             int M, int N, int K)
{
  __shared__ unsigned short As[128][40];
  __shared__ unsigned short Bs[128][40];
  const int t = threadIdx.x;
  const int lane = t & 63, w = t >> 6;
  const int wm = w >> 1, wn = w & 1;
  const int l15 = lane & 15, l4 = lane >> 4;
  const int m0 = blockIdx.y * 128, n0 = blockIdx.x * 128;
  const int srow = t >> 1, scol = (t & 1) * 16;

  f32x4 acc[4][4];
#pragma unroll
  for (int i = 0; i < 4; i++)
#pragma unroll
    for (int j = 0; j < 4; j++) acc[i][j] = zero4();

  const int am = m0 + srow;  // A row this thread stages
  const int bn = n0 + srow;  // B row (output col) this thread stages

  for (int k0 = 0; k0 < K; k0 += 32) {
    short8 av0, av1, bv0, bv1;
    if constexpr (A_BF16) {
      const unsigned short* A = (const unsigned short*)A_;
      if (am < M) {
        const unsigned short* p = A + (size_t)am * K + k0 + scol;
        av0 = *(const short8*)p;
        av1 = *(const short8*)(p + 8);
      } else { av0 = zero8(); av1 = zero8(); }
    } else {
      const float* A = (const float*)A_;
      if (am < M) {
        const float* p = A + (size_t)am * K + k0 + scol;
        f32x4 x0 = *(const f32x4*)(p);
        f32x4 x1 = *(const f32x4*)(p + 4);
        f32x4 x2 = *(const f32x4*)(p + 8);
        f32x4 x3 = *(const f32x4*)(p + 12);
#pragma unroll
        for (int i = 0; i < 4; i++) {
          av0[i]     = (short)f2bf(x0[i]);
          av0[4 + i] = (short)f2bf(x1[i]);
          av1[i]     = (short)f2bf(x2[i]);
          av1[4 + i] = (short)f2bf(x3[i]);
        }
      } else { av0 = zero8(); av1 = zero8(); }
    }
    {
      const float* p = B + (size_t)bn * K + k0 + scol;
      f32x4 x0 = *(const f32x4*)(p);
      f32x4 x1 = *(const f32x4*)(p + 4);
      f32x4 x2 = *(const f32x4*)(p + 8);
      f32x4 x3 = *(const f32x4*)(p + 12);
#pragma unroll
      for (int i = 0; i < 4; i++) {
        bv0[i]     = (short)f2bf(x0[i]);
        bv0[4 + i] = (short)f2bf(x1[i]);
        bv1[i]     = (short)f2bf(x2[i]);
        bv1[4 + i] = (short)f2bf(x3[i]);
      }
    }
    __syncthreads();  // previous iteration's LDS reads complete
    *(short8*)&As[srow][scol]     = av0;
    *(short8*)&As[srow][scol + 8] = av1;
    *(short8*)&Bs[srow][scol]     = bv0;
    *(short8*)&Bs[srow][scol + 8] = bv1;
    __syncthreads();  // tiles ready

    short8 af[4], bf[4];
#pragma unroll
    for (int mt = 0; mt < 4; mt++)
      af[mt] = *(const short8*)&As[wm * 64 + mt * 16 + l15][l4 * 8];
#pragma unroll
    for (int nt = 0; nt < 4; nt++)
      bf[nt] = *(const short8*)&Bs[wn * 64 + nt * 16 + l15][l4 * 8];
#pragma unroll
    for (int mt = 0; mt < 4; mt++)
#pragma unroll
      for (int nt = 0; nt < 4; nt++)
        acc[mt][nt] = __builtin_amdgcn_mfma_f32_16x16x32_bf16(af[mt], bf[nt], acc[mt][nt], 0, 0, 0);
  }

#pragma unroll
  for (int nt = 0; nt < 4; nt++) {
    const int col = n0 + wn * 64 + nt * 16 + l15;
    const float bvv = bias[col];
#pragma unroll
    for (int mt = 0; mt < 4; mt++) {
#pragma unroll
      for (int j = 0; j < 4; j++) {
        const int row = m0 + wm * 64 + mt * 16 + l4 * 4 + j;
        if (row < M) {
          float val = acc[mt][nt][j] + bvv;
          if constexpr (C_BF16)
            ((unsigned short*)C_)[(size_t)row * N + col] = f2bf(val);
          else
            ((float*)C_)[(size_t)row * N + col] = val;
        }
      }
    }
  }
}

// Fused flash attention. Grid: (B*H)*16 blocks; block = 4 waves, each wave
// owns 16 query rows (64 q-rows/block). KV tiles of 32 with online softmax.
// Q,K,V bf16 in ws as [8192][1024] / [1000][1024]; out bf16 [8192][1024].
__global__ __launch_bounds__(256)
void attn_fused(const unsigned short* __restrict__ Q,
                const unsigned short* __restrict__ Kb,
                const unsigned short* __restrict__ Vb,
                unsigned short* __restrict__ Ob)
{
  const int S = 1000;
  __shared__ unsigned short Ks[32][136];  // K tile, row-major [s][e], padded
  __shared__ unsigned short Vt[128][40];  // V tile transposed [e][s], padded
  __shared__ unsigned short Ps[4][16][40];  // per-wave P transpose buffer

  const int t = threadIdx.x;
  const int lane = t & 63, w = t >> 6;
  const int l15 = lane & 15, l4 = lane >> 4;
  const int qt = blockIdx.x & 15, bh = blockIdx.x >> 4;
  const int b = bh >> 3, h = bh & 7;
  const int qrow0 = b * 1024 + qt * 64 + w * 16;  // this wave's first q row

  // Q fragments in registers: 16 rows x 128 e
  short8 qf[4];
  {
    const unsigned short* qp = Q + (size_t)(qrow0 + l15) * 1024 + h * 128;
#pragma unroll
    for (int kk = 0; kk < 4; kk++)
      qf[kk] = *(const short8*)(qp + kk * 32 + l4 * 8);
  }

  f32x4 o[8];
#pragma unroll
  for (int i = 0; i < 8; i++) o[i] = zero4();
  float m_s[4], l_s[4];
#pragma unroll
  for (int j = 0; j < 4; j++) { m_s[j] = -__builtin_inff(); l_s[j] = 0.f; }

  const int sr = t >> 3;          // staging row 0..31 (key index in tile)
  const int sc0 = (t & 7) * 16;   // staging col (e offset)
  const float scale = 0.08838834764831843f;  // 1/sqrt(128)
  const int sg0 = l15, sg1 = 16 + l15;

  for (int s0 = 0; s0 < S; s0 += 32) {
    // ---- stage K tile (row-major) and V tile (transposed) ----
    short8 kv0, kv1, vv0, vv1;
    if (s0 + sr < S) {
      const unsigned short* kp = Kb + (size_t)(s0 + sr) * 1024 + h * 128 + sc0;
      kv0 = *(const short8*)kp;
      kv1 = *(const short8*)(kp + 8);
      const unsigned short* vp = Vb + (size_t)(s0 + sr) * 1024 + h * 128 + sc0;
      vv0 = *(const short8*)vp;
      vv1 = *(const short8*)(vp + 8);
    } else { kv0 = zero8(); kv1 = zero8(); vv0 = zero8(); vv1 = zero8(); }
    __syncthreads();  // previous iteration's compute done
    *(short8*)&Ks[sr][sc0]     = kv0;
    *(short8*)&Ks[sr][sc0 + 8] = kv1;
#pragma unroll
    for (int i = 0; i < 8; i++) {
      Vt[sc0 + i][sr]     = (unsigned short)vv0[i];
      Vt[sc0 + 8 + i][sr] = (unsigned short)vv1[i];
    }
    __syncthreads();  // tiles ready

    // ---- scores: 16x32 per wave ----
    f32x4 st[2];
    st[0] = zero4(); st[1] = zero4();
#pragma unroll
    for (int sc = 0; sc < 2; sc++)
#pragma unroll
      for (int kk = 0; kk < 4; kk++) {
        short8 kf = *(const short8*)&Ks[sc * 16 + l15][kk * 32 + l4 * 8];
        st[sc] = __builtin_amdgcn_mfma_f32_16x16x32_bf16(qf[kk], kf, st[sc], 0, 0, 0);
      }

    // ---- online softmax update ----
    float p0[4], p1[4];
    const int v0ok = (s0 + sg0) < S, v1ok = (s0 + sg1) < S;
#pragma unroll
    for (int j = 0; j < 4; j++) {
      float a0 = v0ok ? st[0][j] * scale : -__builtin_inff();
      float a1 = v1ok ? st[1][j] * scale : -__builtin_inff();
      float tm = fmaxf(a0, a1);
#pragma unroll
      for (int mk = 1; mk < 16; mk <<= 1) tm = fmaxf(tm, __shfl_xor(tm, mk, 16));
      float mn = fmaxf(m_s[j], tm);
      float alpha = __expf(m_s[j] - mn);
      float e0 = __expf(a0 - mn);
      float e1 = __expf(a1 - mn);
      float rs = e0 + e1;
#pragma unroll
      for (int mk = 1; mk < 16; mk <<= 1) rs += __shfl_xor(rs, mk, 16);
      l_s[j] = l_s[j] * alpha + rs;
      m_s[j] = mn;
#pragma unroll
      for (int e = 0; e < 8; e++) o[e][j] *= alpha;
      p0[j] = e0; p1[j] = e1;
    }

    // ---- transpose P through per-wave LDS into A-fragment layout ----
#pragma unroll
    for (int j = 0; j < 4; j++) {
      Ps[w][l4 * 4 + j][l15]      = f2bf(p0[j]);
      Ps[w][l4 * 4 + j][16 + l15] = f2bf(p1[j]);
    }
    asm volatile("s_waitcnt lgkmcnt(0)" ::: "memory");
    __builtin_amdgcn_sched_barrier(0);
    short8 pf = *(const short8*)&Ps[w][l15][l4 * 8];

    // ---- PV: accumulate 16x128 ----
#pragma unroll
    for (int et = 0; et < 8; et++) {
      short8 vf = *(const short8*)&Vt[et * 16 + l15][l4 * 8];
      o[et] = __builtin_amdgcn_mfma_f32_16x16x32_bf16(pf, vf, o[et], 0, 0, 0);
    }
  }

  // ---- epilogue: normalize and store bf16 ----
  float inv[4];
#pragma unroll
  for (int j = 0; j < 4; j++) inv[j] = 1.f / l_s[j];
  unsigned short* op = Ob + (size_t)qrow0 * 1024 + h * 128;
#pragma unroll
  for (int et = 0; et < 8; et++)
#pragma unroll
    for (int j = 0; j < 4; j++)
      op[(size_t)(l4 * 4 + j) * 1024 + et * 16 + l15] = f2bf(o[et][j] * inv[j]);
}

extern "C" void kernel_launch(void* const* d_in, const int* in_sizes, int n_in,
                              void* d_out, int out_size, void* d_ws, size_t ws_size,
                              hipStream_t stream) {
  const float* target = (const float*)d_in[0];   // [8192,1024]
  const float* source = (const float*)d_in[1];   // [1000,4096]
  const float* value  = (const float*)d_in[2];   // [1000,4096]
  const float* Wq = (const float*)d_in[3];       // [1024,1024]
  const float* bq = (const float*)d_in[4];
  const float* Wk = (const float*)d_in[5];       // [1024,4096]
  const float* bk = (const float*)d_in[6];
  const float* Wv = (const float*)d_in[7];       // [1024,4096]
  const float* bv = (const float*)d_in[8];
  const float* Wo = (const float*)d_in[9];       // [4096,1024]
  const float* bo = (const float*)d_in[10];
  float* out = (float*)d_out;

  char* ws = (char*)d_ws;
  unsigned short* Qb = (unsigned short*)(ws);                 // 8192*1024*2 = 16777216
  unsigned short* Kb = (unsigned short*)(ws + 16777216);      // 1000*1024*2 = 2048000
  unsigned short* Vb = (unsigned short*)(ws + 18825216);      // 2048000
  unsigned short* Ab = (unsigned short*)(ws + 20873216);      // 16777216 -> total 37650432 B

  dim3 blk(256);
  // Q = target @ Wq^T + bq   [8192,1024]
  gemm_bt<false, true><<<dim3(1024 / 128, 8192 / 128), blk, 0, stream>>>(
      (const void*)target, Wq, bq, (void*)Qb, 8192, 1024, 1024);
  // K = source @ Wk^T + bk   [1000,1024]
  gemm_bt<false, true><<<dim3(1024 / 128, 8), blk, 0, stream>>>(
      (const void*)source, Wk, bk, (void*)Kb, 1000, 1024, 4096);
  // V = value @ Wv^T + bv    [1000,1024]
  gemm_bt<false, true><<<dim3(1024 / 128, 8), blk, 0, stream>>>(
      (const void*)value, Wv, bv, (void*)Vb, 1000, 1024, 4096);
  // fused cross-attention -> Ab [8192,1024] bf16
  attn_fused<<<dim3(64 * 16), blk, 0, stream>>>(Qb, Kb, Vb, Ab);
  // out = Ab @ Wo^T + bo     [8192,4096] fp32
  gemm_bt<true, false><<<dim3(4096 / 128, 8192 / 128), blk, 0, stream>>>(
      (const void*)Ab, Wo, bo, (void*)out, 8192, 4096, 1024);
}

// Round 2
// 448.042 us; speedup vs baseline: 1.6603x; 1.6603x over previous
//
#include <hip/hip_runtime.h>
#include <hip/hip_bf16.h>

// EnhancedReprogrammingLayer: Q/K/V projections (bf16 MFMA), fused flash
// cross-attention over S=1000 prototypes, output projection to 4096.
// B=8, L=1024, H=8, E=128, D_MODEL=1024, D_LLM=4096, dk=1024.
//
// R1: K/V projections were 2x215us (64-block grids -> 3% occupancy,
// latency-bound). Replaced by fused K+V split-K GEMM (512 blocks) +
// fp32-partial reduce. Partials overlap the Ab ws region (consumed
// before attention writes Ab).

typedef __attribute__((ext_vector_type(8))) short short8;
typedef __attribute__((ext_vector_type(4))) short short4v;
typedef __attribute__((ext_vector_type(4))) float f32x4;

#define DEVINL static __device__ __forceinline__

DEVINL unsigned short f2bf(float f) {
  union { float f; unsigned u; } v; v.f = f;
  unsigned r = v.u + 0x7FFFu + ((v.u >> 16) & 1u);
  return (unsigned short)(r >> 16);
}

DEVINL f32x4 zero4() { f32x4 z; z[0] = 0.f; z[1] = 0.f; z[2] = 0.f; z[3] = 0.f; return z; }
DEVINL short8 zero8() { short8 z; z[0]=0; z[1]=0; z[2]=0; z[3]=0; z[4]=0; z[5]=0; z[6]=0; z[7]=0; return z; }

// C[M][N] = A[M][K] @ B[N][K]^T + bias.  A fp32 or bf16(ushort); B,bias fp32.
// Block tile 128x128, BK=32, 4 waves in 2x2, each wave 64x64 (4x4 MFMA tiles).
template<bool A_BF16, bool C_BF16>
__global__ __launch_bounds__(256)
void gemm_bt(const void* __restrict__ A_, const float* __restrict__ B,
             const float* __restrict__ bias, void* __restrict__ C_,
             int M, int N, int K)
{
  __shared__ unsigned short As[128][40];
  __shared__ unsigned short Bs[128][40];
  const int t = threadIdx.x;
  const int lane = t & 63, w = t >> 6;
  const int wm = w >> 1, wn = w & 1;
  const int l15 = lane & 15, l4 = lane >> 4;
  const int m0 = blockIdx.y * 128, n0 = blockIdx.x * 128;
  const int srow = t >> 1, scol = (t & 1) * 16;

  f32x4 acc[4][4];
#pragma unroll
  for (int i = 0; i < 4; i++)
#pragma unroll
    for (int j = 0; j < 4; j++) acc[i][j] = zero4();

  const int am = m0 + srow;  // A row this thread stages
  const int bn = n0 + srow;  // B row (output col) this thread stages

  for (int k0 = 0; k0 < K; k0 += 32) {
    short8 av0, av1, bv0, bv1;
    if constexpr (A_BF16) {
      const unsigned short* A = (const unsigned short*)A_;
      if (am < M) {
        const unsigned short* p = A + (size_t)am * K + k0 + scol;
        av0 = *(const short8*)p;
        av1 = *(const short8*)(p + 8);
      } else { av0 = zero8(); av1 = zero8(); }
    } else {
      const float* A = (const float*)A_;
      if (am < M) {
        const float* p = A + (size_t)am * K + k0 + scol;
        f32x4 x0 = *(const f32x4*)(p);
        f32x4 x1 = *(const f32x4*)(p + 4);
        f32x4 x2 = *(const f32x4*)(p + 8);
        f32x4 x3 = *(const f32x4*)(p + 12);
#pragma unroll
        for (int i = 0; i < 4; i++) {
          av0[i]     = (short)f2bf(x0[i]);
          av0[4 + i] = (short)f2bf(x1[i]);
          av1[i]     = (short)f2bf(x2[i]);
          av1[4 + i] = (short)f2bf(x3[i]);
        }
      } else { av0 = zero8(); av1 = zero8(); }
    }
    {
      const float* p = B + (size_t)bn * K + k0 + scol;
      f32x4 x0 = *(const f32x4*)(p);
      f32x4 x1 = *(const f32x4*)(p + 4);
      f32x4 x2 = *(const f32x4*)(p + 8);
      f32x4 x3 = *(const f32x4*)(p + 12);
#pragma unroll
      for (int i = 0; i < 4; i++) {
        bv0[i]     = (short)f2bf(x0[i]);
        bv0[4 + i] = (short)f2bf(x1[i]);
        bv1[i]     = (short)f2bf(x2[i]);
        bv1[4 + i] = (short)f2bf(x3[i]);
      }
    }
    __syncthreads();  // previous iteration's LDS reads complete
    *(short8*)&As[srow][scol]     = av0;
    *(short8*)&As[srow][scol + 8] = av1;
    *(short8*)&Bs[srow][scol]     = bv0;
    *(short8*)&Bs[srow][scol + 8] = bv1;
    __syncthreads();  // tiles ready

    short8 af[4], bf[4];
#pragma unroll
    for (int mt = 0; mt < 4; mt++)
      af[mt] = *(const short8*)&As[wm * 64 + mt * 16 + l15][l4 * 8];
#pragma unroll
    for (int nt = 0; nt < 4; nt++)
      bf[nt] = *(const short8*)&Bs[wn * 64 + nt * 16 + l15][l4 * 8];
#pragma unroll
    for (int mt = 0; mt < 4; mt++)
#pragma unroll
      for (int nt = 0; nt < 4; nt++)
        acc[mt][nt] = __builtin_amdgcn_mfma_f32_16x16x32_bf16(af[mt], bf[nt], acc[mt][nt], 0, 0, 0);
  }

#pragma unroll
  for (int nt = 0; nt < 4; nt++) {
    const int col = n0 + wn * 64 + nt * 16 + l15;
    const float bvv = bias[col];
#pragma unroll
    for (int mt = 0; mt < 4; mt++) {
#pragma unroll
      for (int j = 0; j < 4; j++) {
        const int row = m0 + wm * 64 + mt * 16 + l4 * 4 + j;
        if (row < M) {
          float val = acc[mt][nt][j] + bvv;
          if constexpr (C_BF16)
            ((unsigned short*)C_)[(size_t)row * N + col] = f2bf(val);
          else
            ((float*)C_)[(size_t)row * N + col] = val;
        }
      }
    }
  }
}

// Fused K+V projection with 4-way split-K. Writes fp32 partials (no bias).
// blockIdx.z: bits0-1 = split (K chunk), bit2 = tensor (0=K proj, 1=V proj).
// Pt layout: [(tensor*4+split)][M][N] fp32.
__global__ __launch_bounds__(256)
void gemm_splitk_kv(const float* __restrict__ Src, const float* __restrict__ Val,
                    const float* __restrict__ Wk, const float* __restrict__ Wv,
                    float* __restrict__ Pt, int M, int N, int Ktot)
{
  __shared__ unsigned short As[128][40];
  __shared__ unsigned short Bs[128][40];
  const int t = threadIdx.x;
  const int lane = t & 63, w = t >> 6;
  const int wm = w >> 1, wn = w & 1;
  const int l15 = lane & 15, l4 = lane >> 4;
  const int m0 = blockIdx.y * 128, n0 = blockIdx.x * 128;
  const int srow = t >> 1, scol = (t & 1) * 16;

  const int split = blockIdx.z & 3;
  const int tensor = blockIdx.z >> 2;
  const float* A = tensor ? Val : Src;
  const float* B = tensor ? Wv : Wk;
  const int kchunk = Ktot >> 2;
  const int k_begin = split * kchunk;
  const int k_end = k_begin + kchunk;

  f32x4 acc[4][4];
#pragma unroll
  for (int i = 0; i < 4; i++)
#pragma unroll
    for (int j = 0; j < 4; j++) acc[i][j] = zero4();

  const int am = m0 + srow;
  const int bn = n0 + srow;

  for (int k0 = k_begin; k0 < k_end; k0 += 32) {
    short8 av0, av1, bv0, bv1;
    if (am < M) {
      const float* p = A + (size_t)am * Ktot + k0 + scol;
      f32x4 x0 = *(const f32x4*)(p);
      f32x4 x1 = *(const f32x4*)(p + 4);
      f32x4 x2 = *(const f32x4*)(p + 8);
      f32x4 x3 = *(const f32x4*)(p + 12);
#pragma unroll
      for (int i = 0; i < 4; i++) {
        av0[i]     = (short)f2bf(x0[i]);
        av0[4 + i] = (short)f2bf(x1[i]);
        av1[i]     = (short)f2bf(x2[i]);
        av1[4 + i] = (short)f2bf(x3[i]);
      }
    } else { av0 = zero8(); av1 = zero8(); }
    {
      const float* p = B + (size_t)bn * Ktot + k0 + scol;
      f32x4 x0 = *(const f32x4*)(p);
      f32x4 x1 = *(const f32x4*)(p + 4);
      f32x4 x2 = *(const f32x4*)(p + 8);
      f32x4 x3 = *(const f32x4*)(p + 12);
#pragma unroll
      for (int i = 0; i < 4; i++) {
        bv0[i]     = (short)f2bf(x0[i]);
        bv0[4 + i] = (short)f2bf(x1[i]);
        bv1[i]     = (short)f2bf(x2[i]);
        bv1[4 + i] = (short)f2bf(x3[i]);
      }
    }
    __syncthreads();
    *(short8*)&As[srow][scol]     = av0;
    *(short8*)&As[srow][scol + 8] = av1;
    *(short8*)&Bs[srow][scol]     = bv0;
    *(short8*)&Bs[srow][scol + 8] = bv1;
    __syncthreads();

    short8 af[4], bf[4];
#pragma unroll
    for (int mt = 0; mt < 4; mt++)
      af[mt] = *(const short8*)&As[wm * 64 + mt * 16 + l15][l4 * 8];
#pragma unroll
    for (int nt = 0; nt < 4; nt++)
      bf[nt] = *(const short8*)&Bs[wn * 64 + nt * 16 + l15][l4 * 8];
#pragma unroll
    for (int mt = 0; mt < 4; mt++)
#pragma unroll
      for (int nt = 0; nt < 4; nt++)
        acc[mt][nt] = __builtin_amdgcn_mfma_f32_16x16x32_bf16(af[mt], bf[nt], acc[mt][nt], 0, 0, 0);
  }

  float* C = Pt + (size_t)(tensor * 4 + split) * M * N;
#pragma unroll
  for (int nt = 0; nt < 4; nt++) {
    const int col = n0 + wn * 64 + nt * 16 + l15;
#pragma unroll
    for (int mt = 0; mt < 4; mt++) {
#pragma unroll
      for (int j = 0; j < 4; j++) {
        const int row = m0 + wm * 64 + mt * 16 + l4 * 4 + j;
        if (row < M)
          C[(size_t)row * N + col] = acc[mt][nt][j];
      }
    }
  }
}

// Reduce 4 fp32 split-K partials + bias -> bf16 K/V buffers.
// grid: 2 * M*N/4 / 256 blocks; each thread handles one f32x4.
__global__ __launch_bounds__(256)
void reduce_kv(const float* __restrict__ Pt, const float* __restrict__ bk,
               const float* __restrict__ bv, unsigned short* __restrict__ Kb,
               unsigned short* __restrict__ Vb, int M, int N)
{
  const int per_tensor = (M * N) >> 2;  // vec4 count per tensor
  int idx = blockIdx.x * 256 + threadIdx.x;
  const int tensor = idx >= per_tensor;
  const int e = tensor ? idx - per_tensor : idx;
  const size_t MN = (size_t)M * N;
  const float* base = Pt + (size_t)tensor * 4 * MN + (size_t)e * 4;
  f32x4 s = *(const f32x4*)(base);
#pragma unroll
  for (int sp = 1; sp < 4; sp++) {
    f32x4 p = *(const f32x4*)(base + sp * MN);
    s[0] += p[0]; s[1] += p[1]; s[2] += p[2]; s[3] += p[3];
  }
  const int col0 = (e * 4) & (N - 1);
  const float* bias = tensor ? bv : bk;
  f32x4 bb = *(const f32x4*)(bias + col0);
  short4v o;
#pragma unroll
  for (int j = 0; j < 4; j++) o[j] = (short)f2bf(s[j] + bb[j]);
  unsigned short* out = tensor ? Vb : Kb;
  *(short4v*)(out + (size_t)e * 4) = o;
}

// Fused flash attention. Grid: (B*H)*16 blocks; block = 4 waves, each wave
// owns 16 query rows (64 q-rows/block). KV tiles of 32 with online softmax.
// Q,K,V bf16 in ws as [8192][1024] / [1000][1024]; out bf16 [8192][1024].
__global__ __launch_bounds__(256)
void attn_fused(const unsigned short* __restrict__ Q,
                const unsigned short* __restrict__ Kb,
                const unsigned short* __restrict__ Vb,
                unsigned short* __restrict__ Ob)
{
  const int S = 1000;
  __shared__ unsigned short Ks[32][136];  // K tile, row-major [s][e], padded
  __shared__ unsigned short Vt[128][40];  // V tile transposed [e][s], padded
  __shared__ unsigned short Ps[4][16][40];  // per-wave P transpose buffer

  const int t = threadIdx.x;
  const int lane = t & 63, w = t >> 6;
  const int l15 = lane & 15, l4 = lane >> 4;
  const int qt = blockIdx.x & 15, bh = blockIdx.x >> 4;
  const int b = bh >> 3, h = bh & 7;
  const int qrow0 = b * 1024 + qt * 64 + w * 16;  // this wave's first q row

  // Q fragments in registers: 16 rows x 128 e
  short8 qf[4];
  {
    const unsigned short* qp = Q + (size_t)(qrow0 + l15) * 1024 + h * 128;
#pragma unroll
    for (int kk = 0; kk < 4; kk++)
      qf[kk] = *(const short8*)(qp + kk * 32 + l4 * 8);
  }

  f32x4 o[8];
#pragma unroll
  for (int i = 0; i < 8; i++) o[i] = zero4();
  float m_s[4], l_s[4];
#pragma unroll
  for (int j = 0; j < 4; j++) { m_s[j] = -__builtin_inff(); l_s[j] = 0.f; }

  const int sr = t >> 3;          // staging row 0..31 (key index in tile)
  const int sc0 = (t & 7) * 16;   // staging col (e offset)
  const float scale = 0.08838834764831843f;  // 1/sqrt(128)
  const int sg0 = l15, sg1 = 16 + l15;

  for (int s0 = 0; s0 < S; s0 += 32) {
    // ---- stage K tile (row-major) and V tile (transposed) ----
    short8 kv0, kv1, vv0, vv1;
    if (s0 + sr < S) {
      const unsigned short* kp = Kb + (size_t)(s0 + sr) * 1024 + h * 128 + sc0;
      kv0 = *(const short8*)kp;
      kv1 = *(const short8*)(kp + 8);
      const unsigned short* vp = Vb + (size_t)(s0 + sr) * 1024 + h * 128 + sc0;
      vv0 = *(const short8*)vp;
      vv1 = *(const short8*)(vp + 8);
    } else { kv0 = zero8(); kv1 = zero8(); vv0 = zero8(); vv1 = zero8(); }
    __syncthreads();  // previous iteration's compute done
    *(short8*)&Ks[sr][sc0]     = kv0;
    *(short8*)&Ks[sr][sc0 + 8] = kv1;
#pragma unroll
    for (int i = 0; i < 8; i++) {
      Vt[sc0 + i][sr]     = (unsigned short)vv0[i];
      Vt[sc0 + 8 + i][sr] = (unsigned short)vv1[i];
    }
    __syncthreads();  // tiles ready

    // ---- scores: 16x32 per wave ----
    f32x4 st[2];
    st[0] = zero4(); st[1] = zero4();
#pragma unroll
    for (int sc = 0; sc < 2; sc++)
#pragma unroll
      for (int kk = 0; kk < 4; kk++) {
        short8 kf = *(const short8*)&Ks[sc * 16 + l15][kk * 32 + l4 * 8];
        st[sc] = __builtin_amdgcn_mfma_f32_16x16x32_bf16(qf[kk], kf, st[sc], 0, 0, 0);
      }

    // ---- online softmax update ----
    float p0[4], p1[4];
    const int v0ok = (s0 + sg0) < S, v1ok = (s0 + sg1) < S;
#pragma unroll
    for (int j = 0; j < 4; j++) {
      float a0 = v0ok ? st[0][j] * scale : -__builtin_inff();
      float a1 = v1ok ? st[1][j] * scale : -__builtin_inff();
      float tm = fmaxf(a0, a1);
#pragma unroll
      for (int mk = 1; mk < 16; mk <<= 1) tm = fmaxf(tm, __shfl_xor(tm, mk, 16));
      float mn = fmaxf(m_s[j], tm);
      float alpha = __expf(m_s[j] - mn);
      float e0 = __expf(a0 - mn);
      float e1 = __expf(a1 - mn);
      float rs = e0 + e1;
#pragma unroll
      for (int mk = 1; mk < 16; mk <<= 1) rs += __shfl_xor(rs, mk, 16);
      l_s[j] = l_s[j] * alpha + rs;
      m_s[j] = mn;
#pragma unroll
      for (int e = 0; e < 8; e++) o[e][j] *= alpha;
      p0[j] = e0; p1[j] = e1;
    }

    // ---- transpose P through per-wave LDS into A-fragment layout ----
#pragma unroll
    for (int j = 0; j < 4; j++) {
      Ps[w][l4 * 4 + j][l15]      = f2bf(p0[j]);
      Ps[w][l4 * 4 + j][16 + l15] = f2bf(p1[j]);
    }
    asm volatile("s_waitcnt lgkmcnt(0)" ::: "memory");
    __builtin_amdgcn_sched_barrier(0);
    short8 pf = *(const short8*)&Ps[w][l15][l4 * 8];

    // ---- PV: accumulate 16x128 ----
#pragma unroll
    for (int et = 0; et < 8; et++) {
      short8 vf = *(const short8*)&Vt[et * 16 + l15][l4 * 8];
      o[et] = __builtin_amdgcn_mfma_f32_16x16x32_bf16(pf, vf, o[et], 0, 0, 0);
    }
  }

  // ---- epilogue: normalize and store bf16 ----
  float inv[4];
#pragma unroll
  for (int j = 0; j < 4; j++) inv[j] = 1.f / l_s[j];
  unsigned short* op = Ob + (size_t)qrow0 * 1024 + h * 128;
#pragma unroll
  for (int et = 0; et < 8; et++)
#pragma unroll
    for (int j = 0; j < 4; j++)
      op[(size_t)(l4 * 4 + j) * 1024 + et * 16 + l15] = f2bf(o[et][j] * inv[j]);
}

extern "C" void kernel_launch(void* const* d_in, const int* in_sizes, int n_in,
                              void* d_out, int out_size, void* d_ws, size_t ws_size,
                              hipStream_t stream) {
  const float* target = (const float*)d_in[0];   // [8192,1024]
  const float* source = (const float*)d_in[1];   // [1000,4096]
  const float* value  = (const float*)d_in[2];   // [1000,4096]
  const float* Wq = (const float*)d_in[3];       // [1024,1024]
  const float* bq = (const float*)d_in[4];
  const float* Wk = (const float*)d_in[5];       // [1024,4096]
  const float* bk = (const float*)d_in[6];
  const float* Wv = (const float*)d_in[7];       // [1024,4096]
  const float* bv = (const float*)d_in[8];
  const float* Wo = (const float*)d_in[9];       // [4096,1024]
  const float* bo = (const float*)d_in[10];
  float* out = (float*)d_out;

  char* ws = (char*)d_ws;
  unsigned short* Qb = (unsigned short*)(ws);                 // 8192*1024*2 = 16777216
  unsigned short* Kb = (unsigned short*)(ws + 16777216);      // 1000*1024*2 = 2048000
  unsigned short* Vb = (unsigned short*)(ws + 18825216);      // 2048000
  unsigned short* Ab = (unsigned short*)(ws + 20873216);      // 16777216
  // split-K partials overlap Ab (consumed by reduce_kv before attn writes Ab):
  float* Pt = (float*)(ws + 20873216);                        // 8*1000*1024*4 = 32768000
  const size_t WS_NEED = 20873216 + 32768000;                 // 53.6 MB

  dim3 blk(256);
  // Q = target @ Wq^T + bq   [8192,1024]
  gemm_bt<false, true><<<dim3(1024 / 128, 8192 / 128), blk, 0, stream>>>(
      (const void*)target, Wq, bq, (void*)Qb, 8192, 1024, 1024);

  if (ws_size >= WS_NEED) {
    // Fused K+V projection, 4-way split-K: 8*8*8 = 512 blocks.
    gemm_splitk_kv<<<dim3(8, 8, 8), blk, 0, stream>>>(
        source, value, Wk, Wv, Pt, 1000, 1024, 4096);
    reduce_kv<<<dim3(2 * 1000 * 1024 / 4 / 256), blk, 0, stream>>>(
        Pt, bk, bv, Kb, Vb, 1000, 1024);
  } else {
    // Fallback: original low-occupancy path.
    gemm_bt<false, true><<<dim3(1024 / 128, 8), blk, 0, stream>>>(
        (const void*)source, Wk, bk, (void*)Kb, 1000, 1024, 4096);
    gemm_bt<false, true><<<dim3(1024 / 128, 8), blk, 0, stream>>>(
        (const void*)value, Wv, bv, (void*)Vb, 1000, 1024, 4096);
  }

  // fused cross-attention -> Ab [8192,1024] bf16
  attn_fused<<<dim3(64 * 16), blk, 0, stream>>>(Qb, Kb, Vb, Ab);
  // out = Ab @ Wo^T + bo     [8192,4096] fp32
  gemm_bt<true, false><<<dim3(4096 / 128, 8192 / 128), blk, 0, stream>>>(
      (const void*)Ab, Wo, bo, (void*)out, 8192, 4096, 1024);
}

// Round 3
// 397.534 us; speedup vs baseline: 1.8712x; 1.1271x over previous
//
#include <hip/hip_runtime.h>
#include <hip/hip_bf16.h>

// EnhancedReprogrammingLayer: Q/K/V projections (bf16 MFMA), fused flash
// cross-attention over S=1000 prototypes, output projection to 4096.
// B=8, L=1024, H=8, E=128, D_MODEL=1024, D_LLM=4096, dk=1024.
//
// R1: split-K K/V projection (was 2x215us at 3% occupancy).
// R2: attention rewritten LDS-free: swapped QK^T (mfma(K,Q)) -> in-register
//     softmax (2 shfl_xor), P redistributed via cvt_pk_bf16 + 8 shuffles,
//     V kept transposed in global (written by split-K epilogue + reduce),
//     defer-max rescale threshold, 32 q-rows/wave. Was: 4e7 LDS bank
//     conflicts/dispatch from scalar transpose writes.

typedef __attribute__((ext_vector_type(8))) short short8;
typedef __attribute__((ext_vector_type(4))) short short4v;
typedef __attribute__((ext_vector_type(4))) float f32x4;
typedef __attribute__((ext_vector_type(4))) int int4v;

#define DEVINL static __device__ __forceinline__

DEVINL unsigned short f2bf(float f) {
  union { float f; unsigned u; } v; v.f = f;
  unsigned r = v.u + 0x7FFFu + ((v.u >> 16) & 1u);
  return (unsigned short)(r >> 16);
}

DEVINL f32x4 zero4() { f32x4 z; z[0] = 0.f; z[1] = 0.f; z[2] = 0.f; z[3] = 0.f; return z; }
DEVINL short8 zero8() { short8 z; z[0]=0; z[1]=0; z[2]=0; z[3]=0; z[4]=0; z[5]=0; z[6]=0; z[7]=0; return z; }

// C[M][N] = A[M][K] @ B[N][K]^T + bias.  A fp32 or bf16(ushort); B,bias fp32.
// Block tile 128x128, BK=32, 4 waves in 2x2, each wave 64x64 (4x4 MFMA tiles).
// C_T: write transposed (C[col*1024 + row], bf16) - fallback V^T producer.
template<bool A_BF16, bool C_BF16, bool C_T>
__global__ __launch_bounds__(256)
void gemm_bt(const void* __restrict__ A_, const float* __restrict__ B,
             const float* __restrict__ bias, void* __restrict__ C_,
             int M, int N, int K)
{
  __shared__ unsigned short As[128][40];
  __shared__ unsigned short Bs[128][40];
  const int t = threadIdx.x;
  const int lane = t & 63, w = t >> 6;
  const int wm = w >> 1, wn = w & 1;
  const int l15 = lane & 15, l4 = lane >> 4;
  const int m0 = blockIdx.y * 128, n0 = blockIdx.x * 128;
  const int srow = t >> 1, scol = (t & 1) * 16;

  f32x4 acc[4][4];
#pragma unroll
  for (int i = 0; i < 4; i++)
#pragma unroll
    for (int j = 0; j < 4; j++) acc[i][j] = zero4();

  const int am = m0 + srow;  // A row this thread stages
  const int bn = n0 + srow;  // B row (output col) this thread stages

  for (int k0 = 0; k0 < K; k0 += 32) {
    short8 av0, av1, bv0, bv1;
    if constexpr (A_BF16) {
      const unsigned short* A = (const unsigned short*)A_;
      if (am < M) {
        const unsigned short* p = A + (size_t)am * K + k0 + scol;
        av0 = *(const short8*)p;
        av1 = *(const short8*)(p + 8);
      } else { av0 = zero8(); av1 = zero8(); }
    } else {
      const float* A = (const float*)A_;
      if (am < M) {
        const float* p = A + (size_t)am * K + k0 + scol;
        f32x4 x0 = *(const f32x4*)(p);
        f32x4 x1 = *(const f32x4*)(p + 4);
        f32x4 x2 = *(const f32x4*)(p + 8);
        f32x4 x3 = *(const f32x4*)(p + 12);
#pragma unroll
        for (int i = 0; i < 4; i++) {
          av0[i]     = (short)f2bf(x0[i]);
          av0[4 + i] = (short)f2bf(x1[i]);
          av1[i]     = (short)f2bf(x2[i]);
          av1[4 + i] = (short)f2bf(x3[i]);
        }
      } else { av0 = zero8(); av1 = zero8(); }
    }
    {
      const float* p = B + (size_t)bn * K + k0 + scol;
      f32x4 x0 = *(const f32x4*)(p);
      f32x4 x1 = *(const f32x4*)(p + 4);
      f32x4 x2 = *(const f32x4*)(p + 8);
      f32x4 x3 = *(const f32x4*)(p + 12);
#pragma unroll
      for (int i = 0; i < 4; i++) {
        bv0[i]     = (short)f2bf(x0[i]);
        bv0[4 + i] = (short)f2bf(x1[i]);
        bv1[i]     = (short)f2bf(x2[i]);
        bv1[4 + i] = (short)f2bf(x3[i]);
      }
    }
    __syncthreads();  // previous iteration's LDS reads complete
    *(short8*)&As[srow][scol]     = av0;
    *(short8*)&As[srow][scol + 8] = av1;
    *(short8*)&Bs[srow][scol]     = bv0;
    *(short8*)&Bs[srow][scol + 8] = bv1;
    __syncthreads();  // tiles ready

    short8 af[4], bf[4];
#pragma unroll
    for (int mt = 0; mt < 4; mt++)
      af[mt] = *(const short8*)&As[wm * 64 + mt * 16 + l15][l4 * 8];
#pragma unroll
    for (int nt = 0; nt < 4; nt++)
      bf[nt] = *(const short8*)&Bs[wn * 64 + nt * 16 + l15][l4 * 8];
#pragma unroll
    for (int mt = 0; mt < 4; mt++)
#pragma unroll
      for (int nt = 0; nt < 4; nt++)
        acc[mt][nt] = __builtin_amdgcn_mfma_f32_16x16x32_bf16(af[mt], bf[nt], acc[mt][nt], 0, 0, 0);
  }

#pragma unroll
  for (int nt = 0; nt < 4; nt++) {
    const int col = n0 + wn * 64 + nt * 16 + l15;
    const float bvv = bias[col];
#pragma unroll
    for (int mt = 0; mt < 4; mt++) {
#pragma unroll
      for (int j = 0; j < 4; j++) {
        const int row = m0 + wm * 64 + mt * 16 + l4 * 4 + j;
        if (row < M) {
          float val = acc[mt][nt][j] + bvv;
          if constexpr (C_T)
            ((unsigned short*)C_)[(size_t)col * 1024 + row] = f2bf(val);
          else if constexpr (C_BF16)
            ((unsigned short*)C_)[(size_t)row * N + col] = f2bf(val);
          else
            ((float*)C_)[(size_t)row * N + col] = val;
        }
      }
    }
  }
}

// Fused K+V projection with 4-way split-K. Writes fp32 partials (no bias).
// blockIdx.z: bits0-1 = split (K chunk), bit2 = tensor (0=K proj, 1=V proj).
// K partials: row-major slabs [split][1000][1024] at Pt.
// V partials: TRANSPOSED slabs [split][1024 cols][1024 rows] at Pt+4096000
//             (acc regs are row-consecutive -> f32x4 col-major stores).
__global__ __launch_bounds__(256)
void gemm_splitk_kv(const float* __restrict__ Src, const float* __restrict__ Val,
                    const float* __restrict__ Wk, const float* __restrict__ Wv,
                    float* __restrict__ Pt, int M, int N, int Ktot)
{
  __shared__ unsigned short As[128][40];
  __shared__ unsigned short Bs[128][40];
  const int t = threadIdx.x;
  const int lane = t & 63, w = t >> 6;
  const int wm = w >> 1, wn = w & 1;
  const int l15 = lane & 15, l4 = lane >> 4;
  const int m0 = blockIdx.y * 128, n0 = blockIdx.x * 128;
  const int srow = t >> 1, scol = (t & 1) * 16;

  const int split = blockIdx.z & 3;
  const int tensor = blockIdx.z >> 2;
  const float* A = tensor ? Val : Src;
  const float* B = tensor ? Wv : Wk;
  const int kchunk = Ktot >> 2;
  const int k_begin = split * kchunk;
  const int k_end = k_begin + kchunk;

  f32x4 acc[4][4];
#pragma unroll
  for (int i = 0; i < 4; i++)
#pragma unroll
    for (int j = 0; j < 4; j++) acc[i][j] = zero4();

  const int am = m0 + srow;
  const int bn = n0 + srow;

  for (int k0 = k_begin; k0 < k_end; k0 += 32) {
    short8 av0, av1, bv0, bv1;
    if (am < M) {
      const float* p = A + (size_t)am * Ktot + k0 + scol;
      f32x4 x0 = *(const f32x4*)(p);
      f32x4 x1 = *(const f32x4*)(p + 4);
      f32x4 x2 = *(const f32x4*)(p + 8);
      f32x4 x3 = *(const f32x4*)(p + 12);
#pragma unroll
      for (int i = 0; i < 4; i++) {
        av0[i]     = (short)f2bf(x0[i]);
        av0[4 + i] = (short)f2bf(x1[i]);
        av1[i]     = (short)f2bf(x2[i]);
        av1[4 + i] = (short)f2bf(x3[i]);
      }
    } else { av0 = zero8(); av1 = zero8(); }
    {
      const float* p = B + (size_t)bn * Ktot + k0 + scol;
      f32x4 x0 = *(const f32x4*)(p);
      f32x4 x1 = *(const f32x4*)(p + 4);
      f32x4 x2 = *(const f32x4*)(p + 8);
      f32x4 x3 = *(const f32x4*)(p + 12);
#pragma unroll
      for (int i = 0; i < 4; i++) {
        bv0[i]     = (short)f2bf(x0[i]);
        bv0[4 + i] = (short)f2bf(x1[i]);
        bv1[i]     = (short)f2bf(x2[i]);
        bv1[4 + i] = (short)f2bf(x3[i]);
      }
    }
    __syncthreads();
    *(short8*)&As[srow][scol]     = av0;
    *(short8*)&As[srow][scol + 8] = av1;
    *(short8*)&Bs[srow][scol]     = bv0;
    *(short8*)&Bs[srow][scol + 8] = bv1;
    __syncthreads();

    short8 af[4], bf[4];
#pragma unroll
    for (int mt = 0; mt < 4; mt++)
      af[mt] = *(const short8*)&As[wm * 64 + mt * 16 + l15][l4 * 8];
#pragma unroll
    for (int nt = 0; nt < 4; nt++)
      bf[nt] = *(const short8*)&Bs[wn * 64 + nt * 16 + l15][l4 * 8];
#pragma unroll
    for (int mt = 0; mt < 4; mt++)
#pragma unroll
      for (int nt = 0; nt < 4; nt++)
        acc[mt][nt] = __builtin_amdgcn_mfma_f32_16x16x32_bf16(af[mt], bf[nt], acc[mt][nt], 0, 0, 0);
  }

  if (tensor == 0) {
    float* C = Pt + (size_t)split * 1024000;  // [1000][1024] row-major
#pragma unroll
    for (int nt = 0; nt < 4; nt++) {
      const int col = n0 + wn * 64 + nt * 16 + l15;
#pragma unroll
      for (int mt = 0; mt < 4; mt++) {
#pragma unroll
        for (int j = 0; j < 4; j++) {
          const int row = m0 + wm * 64 + mt * 16 + l4 * 4 + j;
          if (row < M)
            C[(size_t)row * N + col] = acc[mt][nt][j];
        }
      }
    }
  } else {
    float* C = Pt + 4096000 + (size_t)split * 1048576;  // [1024 col][1024 row]
#pragma unroll
    for (int nt = 0; nt < 4; nt++) {
      const int col = n0 + wn * 64 + nt * 16 + l15;
#pragma unroll
      for (int mt = 0; mt < 4; mt++) {
        const int row0 = m0 + wm * 64 + mt * 16 + l4 * 4;
        *(f32x4*)&C[(size_t)col * 1024 + row0] = acc[mt][nt];  // rows 0..1023 ok
      }
    }
  }
}

// Reduce split-K partials + bias. Blocks 0..999: K rows (row-major bf16 out).
// Blocks 1000..2023: V^T (out Vt[n][s], s padded to 1024; pads benign).
__global__ __launch_bounds__(256)
void reduce_kv2(const float* __restrict__ Pt, const float* __restrict__ bk,
                const float* __restrict__ bv, unsigned short* __restrict__ Kb,
                unsigned short* __restrict__ Vt)
{
  const int bid = blockIdx.x;
  const int t = threadIdx.x;
  if (bid < 1000) {
    const int v4 = bid * 256 + t;              // vec4 over [1000][1024]
    const float* base = Pt + (size_t)v4 * 4;
    f32x4 s = *(const f32x4*)(base);
#pragma unroll
    for (int sp = 1; sp < 4; sp++) {
      f32x4 p = *(const f32x4*)(base + (size_t)sp * 1024000);
      s[0] += p[0]; s[1] += p[1]; s[2] += p[2]; s[3] += p[3];
    }
    const int col0 = (v4 * 4) & 1023;
    f32x4 bb = *(const f32x4*)(bk + col0);
    short4v o;
#pragma unroll
    for (int j = 0; j < 4; j++) o[j] = (short)f2bf(s[j] + bb[j]);
    *(short4v*)(Kb + (size_t)v4 * 4) = o;
  } else {
    const int v4 = (bid - 1000) * 256 + t;     // vec4 over [1024][1024]
    const float* base = Pt + 4096000 + (size_t)v4 * 4;
    f32x4 s = *(const f32x4*)(base);
#pragma unroll
    for (int sp = 1; sp < 4; sp++) {
      f32x4 p = *(const f32x4*)(base + (size_t)sp * 1048576);
      s[0] += p[0]; s[1] += p[1]; s[2] += p[2]; s[3] += p[3];
    }
    const int n = (v4 * 4) >> 10;
    const float bb = bv[n];
    short4v o;
#pragma unroll
    for (int j = 0; j < 4; j++) o[j] = (short)f2bf(s[j] + bb);
    *(short4v*)(Vt + (size_t)v4 * 4) = o;
  }
}

// ---------------- LDS-free fused flash attention ----------------
// Swapped QK^T: st = mfma(K,Q) -> lane(g=lane>>4, q=lane&15) holds
// S[s = sc*16+4g+j][q]. Softmax in-register (2 shfl_xor). P redistributed
// to PV A-fragment layout via 4 cvt_pk_bf16 + 8 shuffles + 4 selects.
// V^T read straight from global (L2-resident). 32 q-rows/wave.
template<bool MASK>
DEVINL void attn_tile(const unsigned short* __restrict__ Kh,
                      const unsigned short* __restrict__ Vh,
                      const short8 (&qf)[2][4], f32x4 (&o)[2][8],
                      float (&m_s)[2], float (&l_s)[2],
                      int s0, int g, int q)
{
  const float scale = 0.08838834764831843f;  // 1/sqrt(128)

  short8 kf[2][4];
#pragma unroll
  for (int sc = 0; sc < 2; sc++)
#pragma unroll
    for (int kk = 0; kk < 4; kk++)
      kf[sc][kk] = *(const short8*)(Kh + (size_t)(s0 + sc * 16 + q) * 1024 + kk * 32 + g * 8);
  short8 vf[8];
#pragma unroll
  for (int et = 0; et < 8; et++)
    vf[et] = *(const short8*)(Vh + (size_t)(et * 16 + q) * 1024 + s0 + g * 8);

  f32x4 st[2][2];
#pragma unroll
  for (int qn = 0; qn < 2; qn++)
#pragma unroll
    for (int sc = 0; sc < 2; sc++) {
      st[qn][sc] = zero4();
#pragma unroll
      for (int kk = 0; kk < 4; kk++)
        st[qn][sc] = __builtin_amdgcn_mfma_f32_16x16x32_bf16(kf[sc][kk], qf[qn][kk], st[qn][sc], 0, 0, 0);
    }

#pragma unroll
  for (int qn = 0; qn < 2; qn++) {
    float a[8];
#pragma unroll
    for (int sc = 0; sc < 2; sc++)
#pragma unroll
      for (int j = 0; j < 4; j++) {
        float v = st[qn][sc][j] * scale;
        if (MASK) {
          const int sl = s0 + sc * 16 + 4 * g + j;
          v = (sl < 1000) ? v : -__builtin_inff();
        }
        a[sc * 4 + j] = v;
      }
    float pmax = fmaxf(fmaxf(fmaxf(a[0], a[1]), fmaxf(a[2], a[3])),
                       fmaxf(fmaxf(a[4], a[5]), fmaxf(a[6], a[7])));
    pmax = fmaxf(pmax, __shfl_xor(pmax, 16));
    pmax = fmaxf(pmax, __shfl_xor(pmax, 32));
    // defer-max: rescale only when some row grew past m+8 (rare after tile 0)
    if (!__all(pmax - m_s[qn] <= 8.0f)) {
      const float mn = fmaxf(m_s[qn], pmax);
      const float alpha = __expf(m_s[qn] - mn);
      m_s[qn] = mn;
      l_s[qn] *= alpha;
      float al[4];
#pragma unroll
      for (int j = 0; j < 4; j++) al[j] = __shfl(alpha, (g << 2) + j);
#pragma unroll
      for (int et = 0; et < 8; et++)
#pragma unroll
        for (int j = 0; j < 4; j++) o[qn][et][j] *= al[j];
    }
    float e8[8];
#pragma unroll
    for (int k = 0; k < 8; k++) e8[k] = __expf(a[k] - m_s[qn]);
    float rs = ((e8[0] + e8[1]) + (e8[2] + e8[3])) + ((e8[4] + e8[5]) + (e8[6] + e8[7]));
    rs += __shfl_xor(rs, 16);
    rs += __shfl_xor(rs, 32);
    l_s[qn] += rs;

    int D0, D1, D2, D3;
    asm("v_cvt_pk_bf16_f32 %0, %1, %2" : "=v"(D0) : "v"(e8[0]), "v"(e8[1]));
    asm("v_cvt_pk_bf16_f32 %0, %1, %2" : "=v"(D1) : "v"(e8[2]), "v"(e8[3]));
    asm("v_cvt_pk_bf16_f32 %0, %1, %2" : "=v"(D2) : "v"(e8[4]), "v"(e8[5]));
    asm("v_cvt_pk_bf16_f32 %0, %1, %2" : "=v"(D3) : "v"(e8[6]), "v"(e8[7]));
    const int sA = q + ((g & 1) << 5);
    const int sB = sA + 16;
    const int a0 = __shfl(D0, sA), a1 = __shfl(D1, sA);
    const int a2 = __shfl(D2, sA), a3 = __shfl(D3, sA);
    const int b0 = __shfl(D0, sB), b1 = __shfl(D1, sB);
    const int b2 = __shfl(D2, sB), b3 = __shfl(D3, sB);
    const bool hi = (g >= 2);
    int4v pi;
    pi[0] = hi ? a2 : a0;
    pi[1] = hi ? a3 : a1;
    pi[2] = hi ? b2 : b0;
    pi[3] = hi ? b3 : b1;
    const short8 pf = __builtin_bit_cast(short8, pi);
#pragma unroll
    for (int et = 0; et < 8; et++)
      o[qn][et] = __builtin_amdgcn_mfma_f32_16x16x32_bf16(pf, vf[et], o[qn][et], 0, 0, 0);
  }
}

__global__ __launch_bounds__(256)
void attn_fused2(const unsigned short* __restrict__ Q,
                 const unsigned short* __restrict__ Kb,
                 const unsigned short* __restrict__ Vt,
                 unsigned short* __restrict__ Ob)
{
  const int t = threadIdx.x;
  const int lane = t & 63, w = t >> 6;
  const int g = lane >> 4, q = lane & 15;
  const int qt = blockIdx.x & 7, bh = blockIdx.x >> 3;
  const int b = bh >> 3, h = bh & 7;
  const int qrow0 = b * 1024 + qt * 128 + w * 32;

  const unsigned short* Kh = Kb + h * 128;
  const unsigned short* Vh = Vt + (size_t)h * 128 * 1024;

  short8 qf[2][4];
#pragma unroll
  for (int qn = 0; qn < 2; qn++) {
    const unsigned short* qp = Q + (size_t)(qrow0 + qn * 16 + q) * 1024 + h * 128;
#pragma unroll
    for (int kk = 0; kk < 4; kk++)
      qf[qn][kk] = *(const short8*)(qp + kk * 32 + g * 8);
  }

  f32x4 o[2][8];
#pragma unroll
  for (int qn = 0; qn < 2; qn++)
#pragma unroll
    for (int et = 0; et < 8; et++) o[qn][et] = zero4();
  float m_s[2] = {-__builtin_inff(), -__builtin_inff()};
  float l_s[2] = {0.f, 0.f};

  for (int tile = 0; tile < 31; ++tile)
    attn_tile<false>(Kh, Vh, qf, o, m_s, l_s, tile * 32, g, q);
  attn_tile<true>(Kh, Vh, qf, o, m_s, l_s, 992, g, q);

#pragma unroll
  for (int qn = 0; qn < 2; qn++) {
    const float inv = 1.0f / l_s[qn];
    float invj[4];
#pragma unroll
    for (int j = 0; j < 4; j++) invj[j] = __shfl(inv, (g << 2) + j);
    unsigned short* op = Ob + (size_t)(qrow0 + qn * 16) * 1024 + h * 128;
#pragma unroll
    for (int et = 0; et < 8; et++)
#pragma unroll
      for (int j = 0; j < 4; j++)
        op[(size_t)(4 * g + j) * 1024 + et * 16 + q] = f2bf(o[qn][et][j] * invj[j]);
  }
}

extern "C" void kernel_launch(void* const* d_in, const int* in_sizes, int n_in,
                              void* d_out, int out_size, void* d_ws, size_t ws_size,
                              hipStream_t stream) {
  const float* target = (const float*)d_in[0];   // [8192,1024]
  const float* source = (const float*)d_in[1];   // [1000,4096]
  const float* value  = (const float*)d_in[2];   // [1000,4096]
  const float* Wq = (const float*)d_in[3];       // [1024,1024]
  const float* bq = (const float*)d_in[4];
  const float* Wk = (const float*)d_in[5];       // [1024,4096]
  const float* bk = (const float*)d_in[6];
  const float* Wv = (const float*)d_in[7];       // [1024,4096]
  const float* bv = (const float*)d_in[8];
  const float* Wo = (const float*)d_in[9];       // [4096,1024]
  const float* bo = (const float*)d_in[10];
  float* out = (float*)d_out;

  char* ws = (char*)d_ws;
  unsigned short* Qb = (unsigned short*)(ws);                 // 16,777,216 B
  unsigned short* Kb = (unsigned short*)(ws + 16777216);      // [1000][1024] 2,048,000 B
  unsigned short* Vt = (unsigned short*)(ws + 18825216);      // [1024 n][1024 s] 2,097,152 B
  unsigned short* Ab = (unsigned short*)(ws + 20922368);      // 16,777,216 B
  // split-K partials overlap Ab (consumed by reduce before attn writes Ab):
  float* Pt = (float*)(ws + 20922368);                        // 33,161,216 B
  const size_t WS_NEED = 20922368 + 33161216;                 // 54,083,584

  dim3 blk(256);
  // Q = target @ Wq^T + bq   [8192,1024] bf16
  gemm_bt<false, true, false><<<dim3(1024 / 128, 8192 / 128), blk, 0, stream>>>(
      (const void*)target, Wq, bq, (void*)Qb, 8192, 1024, 1024);

  if (ws_size >= WS_NEED) {
    // Fused K+V projection, 4-way split-K (V partials transposed).
    gemm_splitk_kv<<<dim3(8, 8, 8), blk, 0, stream>>>(
        source, value, Wk, Wv, Pt, 1000, 1024, 4096);
    reduce_kv2<<<dim3(2024), blk, 0, stream>>>(Pt, bk, bv, Kb, Vt);
  } else {
    // Fallback: direct GEMMs (V written transposed via C_T epilogue).
    gemm_bt<false, true, false><<<dim3(1024 / 128, 8), blk, 0, stream>>>(
        (const void*)source, Wk, bk, (void*)Kb, 1000, 1024, 4096);
    gemm_bt<false, true, true><<<dim3(1024 / 128, 8), blk, 0, stream>>>(
        (const void*)value, Wv, bv, (void*)Vt, 1000, 1024, 4096);
  }

  // fused cross-attention -> Ab [8192,1024] bf16  (512 blocks, LDS-free)
  attn_fused2<<<dim3(512), blk, 0, stream>>>(Qb, Kb, Vt, Ab);

  // out = Ab @ Wo^T + bo     [8192,4096] fp32
  gemm_bt<true, false, false><<<dim3(4096 / 128, 8192 / 128), blk, 0, stream>>>(
      (const void*)Ab, Wo, bo, (void*)out, 8192, 4096, 1024);
}

// Round 4
// 327.900 us; speedup vs baseline: 2.2686x; 1.2124x over previous
//
#include <hip/hip_runtime.h>
#include <hip/hip_bf16.h>

// EnhancedReprogrammingLayer: Q/K/V projections (bf16 MFMA), fused flash
// cross-attention over S=1000 prototypes, output projection to 4096.
// B=8, L=1024, H=8, E=128, D_MODEL=1024, D_LLM=4096, dk=1024.
//
// R1: split-K K/V projection (was 2x215us at 3% occupancy).
// R2: LDS-free attention (swapped QK^T, in-register softmax, V^T in global).
// R3: Q-proj and O-proj moved to gemm_bb: pre-converted bf16 operands +
//     global_load_lds(16B) staging, m97 structure (was reg-staged convert,
//     443 TF / MfmaUtil 18%). Split-K partials now live in d_out (dead
//     scratch until final GEMM overwrites it); Ab overlaps dead target-bf16.

typedef __attribute__((ext_vector_type(8))) short short8;
typedef __attribute__((ext_vector_type(4))) short short4v;
typedef __attribute__((ext_vector_type(4))) float f32x4;
typedef __attribute__((ext_vector_type(4))) int int4v;

#define DEVINL static __device__ __forceinline__

DEVINL unsigned short f2bf(float f) {
  union { float f; unsigned u; } v; v.f = f;
  unsigned r = v.u + 0x7FFFu + ((v.u >> 16) & 1u);
  return (unsigned short)(r >> 16);
}

DEVINL f32x4 zero4() { f32x4 z; z[0] = 0.f; z[1] = 0.f; z[2] = 0.f; z[3] = 0.f; return z; }
DEVINL short8 zero8() { short8 z; z[0]=0; z[1]=0; z[2]=0; z[3]=0; z[4]=0; z[5]=0; z[6]=0; z[7]=0; return z; }

DEVINL void load_lds16(const unsigned short* g, unsigned short* l) {
  __builtin_amdgcn_global_load_lds(
      (const __attribute__((address_space(1))) void*)g,
      (__attribute__((address_space(3))) void*)l, 16, 0, 0);
}

// Bulk fp32 -> bf16 conversion for 3 buffers (8 elems/thread).
__global__ __launch_bounds__(256)
void cvt3_bf16(const float* __restrict__ s0, unsigned short* __restrict__ d0, int n0,
               const float* __restrict__ s1, unsigned short* __restrict__ d1, int n1,
               const float* __restrict__ s2, unsigned short* __restrict__ d2, int n2)
{
  int idx = (blockIdx.x * 256 + threadIdx.x) * 8;
  const float* s; unsigned short* d; int rel = idx;
  if (rel < n0) { s = s0; d = d0; }
  else {
    rel -= n0;
    if (rel < n1) { s = s1; d = d1; }
    else { rel -= n1; if (rel >= n2) return; s = s2; d = d2; }
  }
  f32x4 x0 = *(const f32x4*)(s + rel);
  f32x4 x1 = *(const f32x4*)(s + rel + 4);
  short8 o;
#pragma unroll
  for (int j = 0; j < 4; j++) { o[j] = (short)f2bf(x0[j]); o[4 + j] = (short)f2bf(x1[j]); }
  *(short8*)(d + rel) = o;
}

// C[M][N] = A[M][K] @ B[N][K]^T + bias, A and B bf16 in global.
// m97 structure: 128x128 tile, BK=32, LINEAR LDS (global_load_lds needs
// contiguous dest), 4 waves 2x2, 4x4 MFMA tiles/wave.
// Requires M%128==0, N%128==0, K%32==0.
template<bool C_BF16>
__global__ __launch_bounds__(256)
void gemm_bb(const unsigned short* __restrict__ A,
             const unsigned short* __restrict__ B,
             const float* __restrict__ bias, void* __restrict__ C_,
             int M, int N, int K)
{
  __shared__ unsigned short As[4096];  // [128][32] linear
  __shared__ unsigned short Bs[4096];
  const int t = threadIdx.x;
  const int lane = t & 63, w = t >> 6;
  const int wm = w >> 1, wn = w & 1;
  const int l15 = lane & 15, l4 = lane >> 4;
  const int m0 = blockIdx.y * 128, n0 = blockIdx.x * 128;

  // staging: wave w covers tile rows [w*32, w*32+32), 2 issues of 16 rows.
  // lane l, issue i: row = w*32 + i*16 + (l>>2), col = (l&3)*8.
  const int srow = w * 32 + (lane >> 2);
  const int scol = (lane & 3) * 8;
  const unsigned short* Ap = A + (size_t)(m0 + srow) * K + scol;
  const unsigned short* Bp = B + (size_t)(n0 + srow) * K + scol;
  unsigned short* AsW = &As[w * 1024];
  unsigned short* BsW = &Bs[w * 1024];

  f32x4 acc[4][4];
#pragma unroll
  for (int i = 0; i < 4; i++)
#pragma unroll
    for (int j = 0; j < 4; j++) acc[i][j] = zero4();

  for (int k0 = 0; k0 < K; k0 += 32) {
    if (k0) __syncthreads();  // previous iteration's LDS reads complete
    load_lds16(Ap + k0, AsW);
    load_lds16(Ap + k0 + (size_t)16 * K, AsW + 512);
    load_lds16(Bp + k0, BsW);
    load_lds16(Bp + k0 + (size_t)16 * K, BsW + 512);
    __syncthreads();  // vmcnt drained by barrier semantics; tiles ready

    short8 af[4], bf[4];
#pragma unroll
    for (int mt = 0; mt < 4; mt++)
      af[mt] = *(const short8*)&As[(wm * 64 + mt * 16 + l15) * 32 + l4 * 8];
#pragma unroll
    for (int nt = 0; nt < 4; nt++)
      bf[nt] = *(const short8*)&Bs[(wn * 64 + nt * 16 + l15) * 32 + l4 * 8];
#pragma unroll
    for (int mt = 0; mt < 4; mt++)
#pragma unroll
      for (int nt = 0; nt < 4; nt++)
        acc[mt][nt] = __builtin_amdgcn_mfma_f32_16x16x32_bf16(af[mt], bf[nt], acc[mt][nt], 0, 0, 0);
  }

#pragma unroll
  for (int nt = 0; nt < 4; nt++) {
    const int col = n0 + wn * 64 + nt * 16 + l15;
    const float bvv = bias[col];
#pragma unroll
    for (int mt = 0; mt < 4; mt++) {
#pragma unroll
      for (int j = 0; j < 4; j++) {
        const int row = m0 + wm * 64 + mt * 16 + l4 * 4 + j;
        const float val = acc[mt][nt][j] + bvv;
        if constexpr (C_BF16)
          ((unsigned short*)C_)[(size_t)row * N + col] = f2bf(val);
        else
          ((float*)C_)[(size_t)row * N + col] = val;
      }
    }
  }
}

// Fallback reg-staging GEMM (fp32/bf16 A, fp32 B) - used only if ws is small.
template<bool A_BF16, bool C_BF16, bool C_T>
__global__ __launch_bounds__(256)
void gemm_bt(const void* __restrict__ A_, const float* __restrict__ B,
             const float* __restrict__ bias, void* __restrict__ C_,
             int M, int N, int K)
{
  __shared__ unsigned short As[128][40];
  __shared__ unsigned short Bs[128][40];
  const int t = threadIdx.x;
  const int lane = t & 63, w = t >> 6;
  const int wm = w >> 1, wn = w & 1;
  const int l15 = lane & 15, l4 = lane >> 4;
  const int m0 = blockIdx.y * 128, n0 = blockIdx.x * 128;
  const int srow = t >> 1, scol = (t & 1) * 16;

  f32x4 acc[4][4];
#pragma unroll
  for (int i = 0; i < 4; i++)
#pragma unroll
    for (int j = 0; j < 4; j++) acc[i][j] = zero4();

  const int am = m0 + srow;
  const int bn = n0 + srow;

  for (int k0 = 0; k0 < K; k0 += 32) {
    short8 av0, av1, bv0, bv1;
    if constexpr (A_BF16) {
      const unsigned short* A = (const unsigned short*)A_;
      if (am < M) {
        const unsigned short* p = A + (size_t)am * K + k0 + scol;
        av0 = *(const short8*)p;
        av1 = *(const short8*)(p + 8);
      } else { av0 = zero8(); av1 = zero8(); }
    } else {
      const float* A = (const float*)A_;
      if (am < M) {
        const float* p = A + (size_t)am * K + k0 + scol;
        f32x4 x0 = *(const f32x4*)(p);
        f32x4 x1 = *(const f32x4*)(p + 4);
        f32x4 x2 = *(const f32x4*)(p + 8);
        f32x4 x3 = *(const f32x4*)(p + 12);
#pragma unroll
        for (int i = 0; i < 4; i++) {
          av0[i]     = (short)f2bf(x0[i]);
          av0[4 + i] = (short)f2bf(x1[i]);
          av1[i]     = (short)f2bf(x2[i]);
          av1[4 + i] = (short)f2bf(x3[i]);
        }
      } else { av0 = zero8(); av1 = zero8(); }
    }
    {
      const float* p = B + (size_t)bn * K + k0 + scol;
      f32x4 x0 = *(const f32x4*)(p);
      f32x4 x1 = *(const f32x4*)(p + 4);
      f32x4 x2 = *(const f32x4*)(p + 8);
      f32x4 x3 = *(const f32x4*)(p + 12);
#pragma unroll
      for (int i = 0; i < 4; i++) {
        bv0[i]     = (short)f2bf(x0[i]);
        bv0[4 + i] = (short)f2bf(x1[i]);
        bv1[i]     = (short)f2bf(x2[i]);
        bv1[4 + i] = (short)f2bf(x3[i]);
      }
    }
    __syncthreads();
    *(short8*)&As[srow][scol]     = av0;
    *(short8*)&As[srow][scol + 8] = av1;
    *(short8*)&Bs[srow][scol]     = bv0;
    *(short8*)&Bs[srow][scol + 8] = bv1;
    __syncthreads();

    short8 af[4], bf[4];
#pragma unroll
    for (int mt = 0; mt < 4; mt++)
      af[mt] = *(const short8*)&As[wm * 64 + mt * 16 + l15][l4 * 8];
#pragma unroll
    for (int nt = 0; nt < 4; nt++)
      bf[nt] = *(const short8*)&Bs[wn * 64 + nt * 16 + l15][l4 * 8];
#pragma unroll
    for (int mt = 0; mt < 4; mt++)
#pragma unroll
      for (int nt = 0; nt < 4; nt++)
        acc[mt][nt] = __builtin_amdgcn_mfma_f32_16x16x32_bf16(af[mt], bf[nt], acc[mt][nt], 0, 0, 0);
  }

#pragma unroll
  for (int nt = 0; nt < 4; nt++) {
    const int col = n0 + wn * 64 + nt * 16 + l15;
    const float bvv = bias[col];
#pragma unroll
    for (int mt = 0; mt < 4; mt++) {
#pragma unroll
      for (int j = 0; j < 4; j++) {
        const int row = m0 + wm * 64 + mt * 16 + l4 * 4 + j;
        if (row < M) {
          float val = acc[mt][nt][j] + bvv;
          if constexpr (C_T)
            ((unsigned short*)C_)[(size_t)col * 1024 + row] = f2bf(val);
          else if constexpr (C_BF16)
            ((unsigned short*)C_)[(size_t)row * N + col] = f2bf(val);
          else
            ((float*)C_)[(size_t)row * N + col] = val;
        }
      }
    }
  }
}

// Fused K+V projection with 4-way split-K. fp32 partials (no bias) into Pt.
// K partials: row-major slabs [split][1000][1024] at Pt.
// V partials: TRANSPOSED slabs [split][1024][1024] at Pt+4096000.
__global__ __launch_bounds__(256)
void gemm_splitk_kv(const float* __restrict__ Src, const float* __restrict__ Val,
                    const float* __restrict__ Wk, const float* __restrict__ Wv,
                    float* __restrict__ Pt, int M, int N, int Ktot)
{
  __shared__ unsigned short As[128][40];
  __shared__ unsigned short Bs[128][40];
  const int t = threadIdx.x;
  const int lane = t & 63, w = t >> 6;
  const int wm = w >> 1, wn = w & 1;
  const int l15 = lane & 15, l4 = lane >> 4;
  const int m0 = blockIdx.y * 128, n0 = blockIdx.x * 128;
  const int srow = t >> 1, scol = (t & 1) * 16;

  const int split = blockIdx.z & 3;
  const int tensor = blockIdx.z >> 2;
  const float* A = tensor ? Val : Src;
  const float* B = tensor ? Wv : Wk;
  const int kchunk = Ktot >> 2;
  const int k_begin = split * kchunk;
  const int k_end = k_begin + kchunk;

  f32x4 acc[4][4];
#pragma unroll
  for (int i = 0; i < 4; i++)
#pragma unroll
    for (int j = 0; j < 4; j++) acc[i][j] = zero4();

  const int am = m0 + srow;
  const int bn = n0 + srow;

  for (int k0 = k_begin; k0 < k_end; k0 += 32) {
    short8 av0, av1, bv0, bv1;
    if (am < M) {
      const float* p = A + (size_t)am * Ktot + k0 + scol;
      f32x4 x0 = *(const f32x4*)(p);
      f32x4 x1 = *(const f32x4*)(p + 4);
      f32x4 x2 = *(const f32x4*)(p + 8);
      f32x4 x3 = *(const f32x4*)(p + 12);
#pragma unroll
      for (int i = 0; i < 4; i++) {
        av0[i]     = (short)f2bf(x0[i]);
        av0[4 + i] = (short)f2bf(x1[i]);
        av1[i]     = (short)f2bf(x2[i]);
        av1[4 + i] = (short)f2bf(x3[i]);
      }
    } else { av0 = zero8(); av1 = zero8(); }
    {
      const float* p = B + (size_t)bn * Ktot + k0 + scol;
      f32x4 x0 = *(const f32x4*)(p);
      f32x4 x1 = *(const f32x4*)(p + 4);
      f32x4 x2 = *(const f32x4*)(p + 8);
      f32x4 x3 = *(const f32x4*)(p + 12);
#pragma unroll
      for (int i = 0; i < 4; i++) {
        bv0[i]     = (short)f2bf(x0[i]);
        bv0[4 + i] = (short)f2bf(x1[i]);
        bv1[i]     = (short)f2bf(x2[i]);
        bv1[4 + i] = (short)f2bf(x3[i]);
      }
    }
    __syncthreads();
    *(short8*)&As[srow][scol]     = av0;
    *(short8*)&As[srow][scol + 8] = av1;
    *(short8*)&Bs[srow][scol]     = bv0;
    *(short8*)&Bs[srow][scol + 8] = bv1;
    __syncthreads();

    short8 af[4], bf[4];
#pragma unroll
    for (int mt = 0; mt < 4; mt++)
      af[mt] = *(const short8*)&As[wm * 64 + mt * 16 + l15][l4 * 8];
#pragma unroll
    for (int nt = 0; nt < 4; nt++)
      bf[nt] = *(const short8*)&Bs[wn * 64 + nt * 16 + l15][l4 * 8];
#pragma unroll
    for (int mt = 0; mt < 4; mt++)
#pragma unroll
      for (int nt = 0; nt < 4; nt++)
        acc[mt][nt] = __builtin_amdgcn_mfma_f32_16x16x32_bf16(af[mt], bf[nt], acc[mt][nt], 0, 0, 0);
  }

  if (tensor == 0) {
    float* C = Pt + (size_t)split * 1024000;  // [1000][1024] row-major
#pragma unroll
    for (int nt = 0; nt < 4; nt++) {
      const int col = n0 + wn * 64 + nt * 16 + l15;
#pragma unroll
      for (int mt = 0; mt < 4; mt++) {
#pragma unroll
        for (int j = 0; j < 4; j++) {
          const int row = m0 + wm * 64 + mt * 16 + l4 * 4 + j;
          if (row < M)
            C[(size_t)row * N + col] = acc[mt][nt][j];
        }
      }
    }
  } else {
    float* C = Pt + 4096000 + (size_t)split * 1048576;  // [1024 col][1024 row]
#pragma unroll
    for (int nt = 0; nt < 4; nt++) {
      const int col = n0 + wn * 64 + nt * 16 + l15;
#pragma unroll
      for (int mt = 0; mt < 4; mt++) {
        const int row0 = m0 + wm * 64 + mt * 16 + l4 * 4;
        *(f32x4*)&C[(size_t)col * 1024 + row0] = acc[mt][nt];
      }
    }
  }
}

// Reduce split-K partials + bias. Blocks 0..999: K rows; 1000..2023: V^T.
__global__ __launch_bounds__(256)
void reduce_kv2(const float* __restrict__ Pt, const float* __restrict__ bk,
                const float* __restrict__ bv, unsigned short* __restrict__ Kb,
                unsigned short* __restrict__ Vt)
{
  const int bid = blockIdx.x;
  const int t = threadIdx.x;
  if (bid < 1000) {
    const int v4 = bid * 256 + t;
    const float* base = Pt + (size_t)v4 * 4;
    f32x4 s = *(const f32x4*)(base);
#pragma unroll
    for (int sp = 1; sp < 4; sp++) {
      f32x4 p = *(const f32x4*)(base + (size_t)sp * 1024000);
      s[0] += p[0]; s[1] += p[1]; s[2] += p[2]; s[3] += p[3];
    }
    const int col0 = (v4 * 4) & 1023;
    f32x4 bb = *(const f32x4*)(bk + col0);
    short4v o;
#pragma unroll
    for (int j = 0; j < 4; j++) o[j] = (short)f2bf(s[j] + bb[j]);
    *(short4v*)(Kb + (size_t)v4 * 4) = o;
  } else {
    const int v4 = (bid - 1000) * 256 + t;
    const float* base = Pt + 4096000 + (size_t)v4 * 4;
    f32x4 s = *(const f32x4*)(base);
#pragma unroll
    for (int sp = 1; sp < 4; sp++) {
      f32x4 p = *(const f32x4*)(base + (size_t)sp * 1048576);
      s[0] += p[0]; s[1] += p[1]; s[2] += p[2]; s[3] += p[3];
    }
    const int n = (v4 * 4) >> 10;
    const float bb = bv[n];
    short4v o;
#pragma unroll
    for (int j = 0; j < 4; j++) o[j] = (short)f2bf(s[j] + bb);
    *(short4v*)(Vt + (size_t)v4 * 4) = o;
  }
}

// ---------------- LDS-free fused flash attention ----------------
template<bool MASK>
DEVINL void attn_tile(const unsigned short* __restrict__ Kh,
                      const unsigned short* __restrict__ Vh,
                      const short8 (&qf)[2][4], f32x4 (&o)[2][8],
                      float (&m_s)[2], float (&l_s)[2],
                      int s0, int g, int q)
{
  const float scale = 0.08838834764831843f;  // 1/sqrt(128)

  short8 kf[2][4];
#pragma unroll
  for (int sc = 0; sc < 2; sc++)
#pragma unroll
    for (int kk = 0; kk < 4; kk++)
      kf[sc][kk] = *(const short8*)(Kh + (size_t)(s0 + sc * 16 + q) * 1024 + kk * 32 + g * 8);
  short8 vf[8];
#pragma unroll
  for (int et = 0; et < 8; et++)
    vf[et] = *(const short8*)(Vh + (size_t)(et * 16 + q) * 1024 + s0 + g * 8);

  f32x4 st[2][2];
#pragma unroll
  for (int qn = 0; qn < 2; qn++)
#pragma unroll
    for (int sc = 0; sc < 2; sc++) {
      st[qn][sc] = zero4();
#pragma unroll
      for (int kk = 0; kk < 4; kk++)
        st[qn][sc] = __builtin_amdgcn_mfma_f32_16x16x32_bf16(kf[sc][kk], qf[qn][kk], st[qn][sc], 0, 0, 0);
    }

#pragma unroll
  for (int qn = 0; qn < 2; qn++) {
    float a[8];
#pragma unroll
    for (int sc = 0; sc < 2; sc++)
#pragma unroll
      for (int j = 0; j < 4; j++) {
        float v = st[qn][sc][j] * scale;
        if (MASK) {
          const int sl = s0 + sc * 16 + 4 * g + j;
          v = (sl < 1000) ? v : -__builtin_inff();
        }
        a[sc * 4 + j] = v;
      }
    float pmax = fmaxf(fmaxf(fmaxf(a[0], a[1]), fmaxf(a[2], a[3])),
                       fmaxf(fmaxf(a[4], a[5]), fmaxf(a[6], a[7])));
    pmax = fmaxf(pmax, __shfl_xor(pmax, 16));
    pmax = fmaxf(pmax, __shfl_xor(pmax, 32));
    if (!__all(pmax - m_s[qn] <= 8.0f)) {
      const float mn = fmaxf(m_s[qn], pmax);
      const float alpha = __expf(m_s[qn] - mn);
      m_s[qn] = mn;
      l_s[qn] *= alpha;
      float al[4];
#pragma unroll
      for (int j = 0; j < 4; j++) al[j] = __shfl(alpha, (g << 2) + j);
#pragma unroll
      for (int et = 0; et < 8; et++)
#pragma unroll
        for (int j = 0; j < 4; j++) o[qn][et][j] *= al[j];
    }
    float e8[8];
#pragma unroll
    for (int k = 0; k < 8; k++) e8[k] = __expf(a[k] - m_s[qn]);
    float rs = ((e8[0] + e8[1]) + (e8[2] + e8[3])) + ((e8[4] + e8[5]) + (e8[6] + e8[7]));
    rs += __shfl_xor(rs, 16);
    rs += __shfl_xor(rs, 32);
    l_s[qn] += rs;

    int D0, D1, D2, D3;
    asm("v_cvt_pk_bf16_f32 %0, %1, %2" : "=v"(D0) : "v"(e8[0]), "v"(e8[1]));
    asm("v_cvt_pk_bf16_f32 %0, %1, %2" : "=v"(D1) : "v"(e8[2]), "v"(e8[3]));
    asm("v_cvt_pk_bf16_f32 %0, %1, %2" : "=v"(D2) : "v"(e8[4]), "v"(e8[5]));
    asm("v_cvt_pk_bf16_f32 %0, %1, %2" : "=v"(D3) : "v"(e8[6]), "v"(e8[7]));
    const int sA = q + ((g & 1) << 5);
    const int sB = sA + 16;
    const int a0 = __shfl(D0, sA), a1 = __shfl(D1, sA);
    const int a2 = __shfl(D2, sA), a3 = __shfl(D3, sA);
    const int b0 = __shfl(D0, sB), b1 = __shfl(D1, sB);
    const int b2 = __shfl(D2, sB), b3 = __shfl(D3, sB);
    const bool hi = (g >= 2);
    int4v pi;
    pi[0] = hi ? a2 : a0;
    pi[1] = hi ? a3 : a1;
    pi[2] = hi ? b2 : b0;
    pi[3] = hi ? b3 : b1;
    const short8 pf = __builtin_bit_cast(short8, pi);
#pragma unroll
    for (int et = 0; et < 8; et++)
      o[qn][et] = __builtin_amdgcn_mfma_f32_16x16x32_bf16(pf, vf[et], o[qn][et], 0, 0, 0);
  }
}

__global__ __launch_bounds__(256)
void attn_fused2(const unsigned short* __restrict__ Q,
                 const unsigned short* __restrict__ Kb,
                 const unsigned short* __restrict__ Vt,
                 unsigned short* __restrict__ Ob)
{
  const int t = threadIdx.x;
  const int lane = t & 63, w = t >> 6;
  const int g = lane >> 4, q = lane & 15;
  const int qt = blockIdx.x & 7, bh = blockIdx.x >> 3;
  const int b = bh >> 3, h = bh & 7;
  const int qrow0 = b * 1024 + qt * 128 + w * 32;

  const unsigned short* Kh = Kb + h * 128;
  const unsigned short* Vh = Vt + (size_t)h * 128 * 1024;

  short8 qf[2][4];
#pragma unroll
  for (int qn = 0; qn < 2; qn++) {
    const unsigned short* qp = Q + (size_t)(qrow0 + qn * 16 + q) * 1024 + h * 128;
#pragma unroll
    for (int kk = 0; kk < 4; kk++)
      qf[qn][kk] = *(const short8*)(qp + kk * 32 + g * 8);
  }

  f32x4 o[2][8];
#pragma unroll
  for (int qn = 0; qn < 2; qn++)
#pragma unroll
    for (int et = 0; et < 8; et++) o[qn][et] = zero4();
  float m_s[2] = {-__builtin_inff(), -__builtin_inff()};
  float l_s[2] = {0.f, 0.f};

  for (int tile = 0; tile < 31; ++tile)
    attn_tile<false>(Kh, Vh, qf, o, m_s, l_s, tile * 32, g, q);
  attn_tile<true>(Kh, Vh, qf, o, m_s, l_s, 992, g, q);

#pragma unroll
  for (int qn = 0; qn < 2; qn++) {
    const float inv = 1.0f / l_s[qn];
    float invj[4];
#pragma unroll
    for (int j = 0; j < 4; j++) invj[j] = __shfl(inv, (g << 2) + j);
    unsigned short* op = Ob + (size_t)(qrow0 + qn * 16) * 1024 + h * 128;
#pragma unroll
    for (int et = 0; et < 8; et++)
#pragma unroll
      for (int j = 0; j < 4; j++)
        op[(size_t)(4 * g + j) * 1024 + et * 16 + q] = f2bf(o[qn][et][j] * invj[j]);
  }
}

extern "C" void kernel_launch(void* const* d_in, const int* in_sizes, int n_in,
                              void* d_out, int out_size, void* d_ws, size_t ws_size,
                              hipStream_t stream) {
  const float* target = (const float*)d_in[0];   // [8192,1024]
  const float* source = (const float*)d_in[1];   // [1000,4096]
  const float* value  = (const float*)d_in[2];   // [1000,4096]
  const float* Wq = (const float*)d_in[3];       // [1024,1024]
  const float* bq = (const float*)d_in[4];
  const float* Wk = (const float*)d_in[5];       // [1024,4096]
  const float* bk = (const float*)d_in[6];
  const float* Wv = (const float*)d_in[7];       // [1024,4096]
  const float* bv = (const float*)d_in[8];
  const float* Wo = (const float*)d_in[9];       // [4096,1024]
  const float* bo = (const float*)d_in[10];
  float* out = (float*)d_out;

  char* ws = (char*)d_ws;
  // ws layout (48,185,344 B):
  //   Qb  [8192][1024] bf16 @ 0          (16,777,216)
  //   Kb  [1000][1024] bf16 @ 16,777,216 ( 2,048,000)
  //   Vt  [1024][1024] bf16 @ 18,825,216 ( 2,097,152)
  //   Tb  target bf16       @ 20,922,368 (16,777,216)  dead after Q-proj
  //   Ab  attn out bf16     @ 20,922,368 (16,777,216)  overlaps dead Tb
  //   Wqb Wq bf16           @ 37,699,584 ( 2,097,152)
  //   Wob Wo bf16           @ 39,796,736 ( 8,388,608)
  // split-K fp32 partials (33,161,216 B) live in d_out (134 MB), which the
  // final GEMM fully overwrites each call.
  unsigned short* Qb  = (unsigned short*)(ws);
  unsigned short* Kb  = (unsigned short*)(ws + 16777216);
  unsigned short* Vt  = (unsigned short*)(ws + 18825216);
  unsigned short* Tb  = (unsigned short*)(ws + 20922368);
  unsigned short* Ab  = (unsigned short*)(ws + 20922368);
  unsigned short* Wqb = (unsigned short*)(ws + 37699584);
  unsigned short* Wob = (unsigned short*)(ws + 39796736);
  float* Pt = (float*)d_out;
  const size_t WS_NEED = 48185344;

  dim3 blk(256);
  if (ws_size >= WS_NEED) {
    // 1. convert target/Wq/Wo to bf16 (13,631,488 elems, 8/thread)
    cvt3_bf16<<<dim3(6656), blk, 0, stream>>>(
        target, Tb, 8192 * 1024, Wq, Wqb, 1024 * 1024, Wo, Wob, 4096 * 1024);
    // 2. fused K+V projection, 4-way split-K (partials in d_out scratch)
    gemm_splitk_kv<<<dim3(8, 8, 8), blk, 0, stream>>>(
        source, value, Wk, Wv, Pt, 1000, 1024, 4096);
    reduce_kv2<<<dim3(2024), blk, 0, stream>>>(Pt, bk, bv, Kb, Vt);
    // 3. Q = target @ Wq^T + bq   [8192,1024] bf16 (global_load_lds path)
    gemm_bb<true><<<dim3(8, 64), blk, 0, stream>>>(
        Tb, Wqb, bq, (void*)Qb, 8192, 1024, 1024);
    // 4. fused cross-attention -> Ab (overwrites dead Tb)
    attn_fused2<<<dim3(512), blk, 0, stream>>>(Qb, Kb, Vt, Ab);
    // 5. out = Ab @ Wo^T + bo  [8192,4096] fp32 (overwrites Pt scratch)
    gemm_bb<false><<<dim3(32, 64), blk, 0, stream>>>(
        Ab, Wob, bo, (void*)out, 8192, 4096, 1024);
  } else {
    // Fallback: R2-style reg-staging everywhere, Pt still in d_out.
    gemm_bt<false, true, false><<<dim3(8, 64), blk, 0, stream>>>(
        (const void*)target, Wq, bq, (void*)Qb, 8192, 1024, 1024);
    gemm_splitk_kv<<<dim3(8, 8, 8), blk, 0, stream>>>(
        source, value, Wk, Wv, Pt, 1000, 1024, 4096);
    reduce_kv2<<<dim3(2024), blk, 0, stream>>>(Pt, bk, bv, Kb, Vt);
    attn_fused2<<<dim3(512), blk, 0, stream>>>(Qb, Kb, Vt, Ab);
    gemm_bt<true, false, false><<<dim3(32, 64), blk, 0, stream>>>(
        (const void*)Ab, Wo, bo, (void*)out, 8192, 4096, 1024);
  }
}